// Round 3
// baseline (376.961 us; speedup 1.0000x reference)
//
#include <hip/hip_runtime.h>
#include <math.h>

#define NFFT  16000   // = 128 * 125 (true FFT length)
#define NROW  128     // 128-axis (rows)
#define NCCOL 125     // radix-5 axis (contiguous, true columns)
#define LDST  132     // padded LDS row stride in float2 (132 mod 16 = 4 -> bank mixing)
#define DATN  (NROW * LDST)          // 16896 float2 data region
#define DFEAT 2048
#define TPB   1024
#define R2OFF DATN                   // 64-entry w_128^j LUT
#define R5OFF (DATN + 64)            // 125-entry w_125^k LUT
#define LDSN  (DATN + 64 + 125)      // 17085 float2 total

__device__ __forceinline__ float2 cmul(float2 a, float2 b) {
    return make_float2(a.x*b.x - a.y*b.y, a.x*b.y + a.y*b.x);
}
__device__ __forceinline__ float2 cmulc(float2 a, float2 b) {   // a * conj(b)
    return make_float2(a.x*b.x + a.y*b.y, a.y*b.x - a.x*b.y);
}
__device__ __forceinline__ float2 cadd(float2 a, float2 b){ return make_float2(a.x+b.x, a.y+b.y); }
__device__ __forceinline__ float2 csub(float2 a, float2 b){ return make_float2(a.x-b.x, a.y-b.y); }
// e^{i*pi*a}
__device__ __forceinline__ float2 eipi(float a) {
    float s, c;
    sincospif(a, &s, &c);
    return make_float2(c, s);
}

#define C1f 0.30901699437494742f
#define C2f (-0.80901699437494745f)
#define S1f 0.95105651629515357f
#define S2f 0.58778525229247314f

// forward (DIF) radix-5 butterfly, in place, no twiddles
__device__ __forceinline__ void bfly5_fwd(float2& e0, float2& e1, float2& e2,
                                          float2& e3, float2& e4) {
    float2 t1 = cadd(e1, e4), t2 = cadd(e2, e3);
    float2 t3 = csub(e1, e4), t4 = csub(e2, e3);
    float2 f0 = make_float2(e0.x + t1.x + t2.x, e0.y + t1.y + t2.y);
    float2 m1 = make_float2(e0.x + C1f*t1.x + C2f*t2.x, e0.y + C1f*t1.y + C2f*t2.y);
    float2 m2 = make_float2(e0.x + C2f*t1.x + C1f*t2.x, e0.y + C2f*t1.y + C1f*t2.y);
    float2 v1 = make_float2(S1f*t3.x + S2f*t4.x, S1f*t3.y + S2f*t4.y);
    float2 v2 = make_float2(S2f*t3.x - S1f*t4.x, S2f*t3.y - S1f*t4.y);
    e0 = f0;
    e1 = make_float2(m1.x + v1.y, m1.y - v1.x);   // m1 - i v1
    e4 = make_float2(m1.x - v1.y, m1.y + v1.x);   // m1 + i v1
    e2 = make_float2(m2.x + v2.y, m2.y - v2.x);   // m2 - i v2
    e3 = make_float2(m2.x - v2.y, m2.y + v2.x);   // m2 + i v2
}
// inverse (DIT) radix-5 butterfly, in place, no twiddles
__device__ __forceinline__ void bfly5_inv(float2& e0, float2& e1, float2& e2,
                                          float2& e3, float2& e4) {
    float2 t1 = cadd(e1, e4), t2 = cadd(e2, e3);
    float2 t3 = csub(e1, e4), t4 = csub(e2, e3);
    float2 f0 = make_float2(e0.x + t1.x + t2.x, e0.y + t1.y + t2.y);
    float2 m1 = make_float2(e0.x + C1f*t1.x + C2f*t2.x, e0.y + C1f*t1.y + C2f*t2.y);
    float2 m2 = make_float2(e0.x + C2f*t1.x + C1f*t2.x, e0.y + C2f*t1.y + C1f*t2.y);
    float2 v1 = make_float2(S1f*t3.x + S2f*t4.x, S1f*t3.y + S2f*t4.y);
    float2 v2 = make_float2(S2f*t3.x - S1f*t4.x, S2f*t3.y - S1f*t4.y);
    e0 = f0;
    e1 = make_float2(m1.x - v1.y, m1.y + v1.x);   // m1 + i v1
    e4 = make_float2(m1.x + v1.y, m1.y - v1.x);   // m1 - i v1
    e2 = make_float2(m2.x - v2.y, m2.y + v2.x);   // m2 + i v2
    e3 = make_float2(m2.x + v2.y, m2.y - v2.x);   // m2 - i v2
}

// PADDED cross-twiddle LUT: ws[row*132 + c] = exp(-2*pi*i * c * brev7(row) / N)
// for c < 125; pad entries (c = 125..131) set to finite zeros.
__global__ void fill_cross_lut_pad(float2* __restrict__ ws) {
    int p = blockIdx.x * 256 + threadIdx.x;
    if (p < DATN) {
        int r  = p / LDST;
        int c  = p - r * LDST;
        float2 v = make_float2(0.f, 0.f);
        if (c < NCCOL) {
            int k1 = __brev((unsigned)r) >> 25;
            v = eipi((float)(c * k1) * (-2.0f / (float)NFFT));
        }
        ws[p] = v;
    }
}

// One block per batch row. LDS: 128x132 padded float2 grid + twiddle LUTs.
// Forward: z = sk_img + i*sk_seq ; Z = FFT(z) (DIF four-step 128x125,
//          radix-8 + radix-16(+cross) on the 128 axis, radix-5^3 on 125)
// FSQ: forward L=5 + spectrum square + inverse L=5, one fused contiguous pass
// Inverse: mirror DIT, natural-order output; out = Im(w)/(2N) fused into last pass.
//
// Layout/occupancy notes:
//  - Row stride padded 125 -> 132: row-axis passes index by >>7 / &127 (no
//    div), get exact item counts (F2/I3 = 1024 = one warp-exact pass), and
//    every wave has a CONSTANT row id -> W2L twiddle reads are wave-uniform
//    broadcasts (were per-lane vector reads straddling rows at stride 125).
//    132 mod 16 = 4 keeps radix-5 column patterns spread across banks.
//  - Pad columns 125..127 are zeroed and never touched by radix-5 passes;
//    row passes compute zeros there; output store is guarded c < 125.
//  - LDS (136.7 KB) caps residency at 1 block/CU = 4 waves/SIMD;
//    amdgpu_waves_per_eu(4,4) pins the register allocator to that tier.
//  - Radix-25 unfused into radix-5 pairs (F3a/F3b, I2a/I2b): all lanes
//    active, ~10 VGPR live set (no spills).
__global__ void __launch_bounds__(TPB) __attribute__((amdgpu_waves_per_eu(4, 4)))
mcb_fft_conv_kernel(const float* __restrict__ img, const float* __restrict__ seq,
                    const int* __restrict__ hvec, const float* __restrict__ svec,
                    float* __restrict__ out, const float2* __restrict__ cross)
{
    extern __shared__ float2 buf[];
    const int tid = threadIdx.x;
    const int b   = blockIdx.x;

    #define W2L(k) buf[R2OFF + (k)]
    #define R5L(k) buf[R5OFF + (k)]

    // cross twiddle by (row, col): padded LUT or inline compute
    auto CW = [&](int row, int c) -> float2 {
        if (cross) return cross[row * LDST + c];
        int k1 = __brev((unsigned)row) >> 25;
        return eipi((float)(c * k1) * (-2.0f / (float)NFFT));
    };

    // ---- zero data region (vectorized) + build LDS twiddle LUTs
    {
        float4* b4 = (float4*)buf;                 // 16896 float2 = 8448 float4
        for (int p = tid; p < DATN / 2; p += TPB) b4[p] = make_float4(0.f, 0.f, 0.f, 0.f);
    }
    if (tid < 64) {
        W2L(tid) = eipi(-(float)tid * (1.0f / 64.0f));        // w_128^j
    } else if (tid < 64 + 125) {
        int k = tid - 64;
        R5L(k) = eipi((float)k * (-2.0f / 125.0f));           // w_125^k
    }
    __syncthreads();

    // ---- count-sketch scatter (img -> re, seq -> im), h mapped to padded addr
    {
        const float* irow = img + (size_t)b * DFEAT;
        const float* qrow = seq + (size_t)b * DFEAT;
        #pragma unroll
        for (int it = 0; it < DFEAT / TPB; ++it) {
            const int j = tid + (it << 10);
            float sj = svec[j];
            int   hj = hvec[j];
            int   hr = hj / NCCOL;
            int   ha = hr * LDST + (hj - hr * NCCOL);
            atomicAdd(&buf[ha].x, irow[j] * sj);
            atomicAdd(&buf[ha].y, qrow[j] * sj);
        }
    }
    __syncthreads();

    // ======== F1: forward radix-8, stages ls=6,5,4  (rows j + 16t) ========
    #pragma unroll
    for (int it = 0; it < 2; ++it) {
        const int idx = tid + (it << 10);   // 0..2047
        const int j = idx >> 7;             // 0..15
        const int c = idx & 127;
        const int base = j * LDST + c;
        float2 x[8];
        #pragma unroll
        for (int t = 0; t < 8; ++t) x[t] = buf[base + 16 * LDST * t];
        // ls=6 (dist 4): twiddle w128^{j+16t}
        #pragma unroll
        for (int t = 0; t < 4; ++t) {
            float2 u = x[t], v = x[t+4];
            x[t]   = cadd(u, v);
            x[t+4] = cmul(csub(u, v), W2L(j + 16*t));
        }
        // ls=5 (dist 2): twiddle w128^{2(j+16t)}, t=0,1
        #pragma unroll
        for (int q = 0; q < 8; q += 4)
            #pragma unroll
            for (int t = 0; t < 2; ++t) {
                float2 u = x[q+t], v = x[q+t+2];
                x[q+t]   = cadd(u, v);
                x[q+t+2] = cmul(csub(u, v), W2L(2*(j + 16*t)));
            }
        // ls=4 (dist 1): twiddle w128^{4j}
        {
            float2 w = W2L(4*j);
            #pragma unroll
            for (int q = 0; q < 8; q += 2) {
                float2 u = x[q], v = x[q+1];
                x[q]   = cadd(u, v);
                x[q+1] = cmul(csub(u, v), w);
            }
        }
        #pragma unroll
        for (int t = 0; t < 8; ++t) buf[base + 16 * LDST * t] = x[t];
    }
    __syncthreads();

    // ======== F2: forward radix-16, stages ls=3..0 + cross twiddle (rows 16g+t) ====
    {
        const int g = tid >> 7;             // 0..7
        const int c = tid & 127;
        const int base = g * (16 * LDST) + c;
        const int row0 = g << 4;
        float2 x[16];
        #pragma unroll
        for (int t = 0; t < 16; ++t) x[t] = buf[base + LDST * t];
        // ls=3 (dist 8): twiddle w128^{8t}
        #pragma unroll
        for (int t = 0; t < 8; ++t) {
            float2 u = x[t], v = x[t+8];
            x[t]   = cadd(u, v);
            x[t+8] = cmul(csub(u, v), W2L(8*t));
        }
        // ls=2 (dist 4): twiddle w128^{16t}, t=0..3
        #pragma unroll
        for (int q = 0; q < 16; q += 8)
            #pragma unroll
            for (int t = 0; t < 4; ++t) {
                float2 u = x[q+t], v = x[q+t+4];
                x[q+t]   = cadd(u, v);
                x[q+t+4] = cmul(csub(u, v), W2L(16*t));
            }
        // ls=1 (dist 2): twiddle w128^{32t}, t=0,1
        #pragma unroll
        for (int q = 0; q < 16; q += 4)
            #pragma unroll
            for (int t = 0; t < 2; ++t) {
                float2 u = x[q+t], v = x[q+t+2];
                x[q+t]   = cadd(u, v);
                x[q+t+2] = cmul(csub(u, v), W2L(32*t));
            }
        // ls=0 (dist 1): twiddle 1
        #pragma unroll
        for (int q = 0; q < 16; q += 2) {
            float2 u = x[q], v = x[q+1];
            x[q]   = cadd(u, v);
            x[q+1] = csub(u, v);
        }
        // cross twiddle (row 16g+t, col c)
        #pragma unroll
        for (int t = 0; t < 16; ++t)
            buf[base + LDST * t] = cmul(x[t], CW(row0 + t, c));
    }
    __syncthreads();

    // ======== F3a: forward radix-5, span 25 (items (r, m), m = c mod 25) ========
    for (int idx = tid; idx < 128 * 25; idx += TPB) {
        const int r = idx / 25;
        const int m = idx - r * 25;
        const int base = r * LDST + m;
        float2 x0 = buf[base],      x1 = buf[base + 25], x2 = buf[base + 50],
               x3 = buf[base + 75], x4 = buf[base + 100];
        bfly5_fwd(x0, x1, x2, x3, x4);
        x1 = cmul(x1, R5L(m));
        x2 = cmul(x2, R5L(2*m));
        x3 = cmul(x3, R5L(3*m));
        x4 = cmul(x4, R5L(4*m));
        buf[base] = x0; buf[base + 25] = x1; buf[base + 50] = x2;
        buf[base + 75] = x3; buf[base + 100] = x4;
    }
    __syncthreads();

    // ======== F3b: forward radix-5, span 5 (items (r, j2, t5)) ========
    for (int idx = tid; idx < 128 * 25; idx += TPB) {
        const int r  = idx / 25;
        const int s  = idx - r * 25;
        const int t5 = s / 5;
        const int j2 = s - t5 * 5;
        const int base = r * LDST + j2 + 25 * t5;
        float2 x0 = buf[base],      x1 = buf[base + 5],  x2 = buf[base + 10],
               x3 = buf[base + 15], x4 = buf[base + 20];
        bfly5_fwd(x0, x1, x2, x3, x4);
        x1 = cmul(x1, R5L(5*j2));
        x2 = cmul(x2, R5L(10*j2));
        x3 = cmul(x3, R5L(15*j2));
        x4 = cmul(x4, R5L(20*j2));
        buf[base] = x0; buf[base + 5] = x1; buf[base + 10] = x2;
        buf[base + 15] = x3; buf[base + 20] = x4;
    }
    __syncthreads();

    // ======== FSQ: forward L=5 + spectrum square + inverse L=5 (fused) ========
    for (int idx = tid; idx < 128 * 25; idx += TPB) {
        const int r = idx / 25;
        const int q = idx - r * 25;
        const int base = r * LDST + 5 * q;
        float2 g0 = buf[base], g1 = buf[base+1], g2 = buf[base+2],
               g3 = buf[base+3], g4 = buf[base+4];
        bfly5_fwd(g0, g1, g2, g3, g4);                      // forward stage L=5
        g0 = make_float2(g0.x*g0.x - g0.y*g0.y, 2.f*g0.x*g0.y);   // Z^2
        g1 = make_float2(g1.x*g1.x - g1.y*g1.y, 2.f*g1.x*g1.y);
        g2 = make_float2(g2.x*g2.x - g2.y*g2.y, 2.f*g2.x*g2.y);
        g3 = make_float2(g3.x*g3.x - g3.y*g3.y, 2.f*g3.x*g3.y);
        g4 = make_float2(g4.x*g4.x - g4.y*g4.y, 2.f*g4.x*g4.y);
        bfly5_inv(g0, g1, g2, g3, g4);                      // inverse stage L=5
        buf[base] = g0; buf[base+1] = g1; buf[base+2] = g2;
        buf[base+3] = g3; buf[base+4] = g4;
    }
    __syncthreads();

    // ======== I2a: inverse radix-5, span 5 (items (r, j2, t5)) ========
    for (int idx = tid; idx < 128 * 25; idx += TPB) {
        const int r  = idx / 25;
        const int s  = idx - r * 25;
        const int t5 = s / 5;
        const int j2 = s - t5 * 5;
        const int base = r * LDST + j2 + 25 * t5;
        float2 x0 = buf[base],      x1 = buf[base + 5],  x2 = buf[base + 10],
               x3 = buf[base + 15], x4 = buf[base + 20];
        x1 = cmulc(x1, R5L(5*j2));
        x2 = cmulc(x2, R5L(10*j2));
        x3 = cmulc(x3, R5L(15*j2));
        x4 = cmulc(x4, R5L(20*j2));
        bfly5_inv(x0, x1, x2, x3, x4);
        buf[base] = x0; buf[base + 5] = x1; buf[base + 10] = x2;
        buf[base + 15] = x3; buf[base + 20] = x4;
    }
    __syncthreads();

    // ======== I2b: inverse radix-5, span 25 (items (r, m)) ========
    for (int idx = tid; idx < 128 * 25; idx += TPB) {
        const int r = idx / 25;
        const int m = idx - r * 25;
        const int base = r * LDST + m;
        float2 x0 = buf[base],      x1 = buf[base + 25], x2 = buf[base + 50],
               x3 = buf[base + 75], x4 = buf[base + 100];
        x1 = cmulc(x1, R5L(m));
        x2 = cmulc(x2, R5L(2*m));
        x3 = cmulc(x3, R5L(3*m));
        x4 = cmulc(x4, R5L(4*m));
        bfly5_inv(x0, x1, x2, x3, x4);
        buf[base] = x0; buf[base + 25] = x1; buf[base + 50] = x2;
        buf[base + 75] = x3; buf[base + 100] = x4;
    }
    __syncthreads();

    // ======== I3: inverse radix-16: conj cross + stages ls=0..3 (rows 16g+t) ====
    {
        const int g = tid >> 7;
        const int c = tid & 127;
        const int base = g * (16 * LDST) + c;
        const int row0 = g << 4;
        float2 x[16];
        #pragma unroll
        for (int t = 0; t < 16; ++t)
            x[t] = cmulc(buf[base + LDST * t], CW(row0 + t, c));
        // ls=0 (dist 1): twiddle 1
        #pragma unroll
        for (int q = 0; q < 16; q += 2) {
            float2 u = x[q], v = x[q+1];
            x[q]   = cadd(u, v);
            x[q+1] = csub(u, v);
        }
        // ls=1 (dist 2): conj w128^{32t}
        #pragma unroll
        for (int q = 0; q < 16; q += 4)
            #pragma unroll
            for (int t = 0; t < 2; ++t) {
                float2 u = x[q+t];
                float2 v = cmulc(x[q+t+2], W2L(32*t));
                x[q+t]   = cadd(u, v);
                x[q+t+2] = csub(u, v);
            }
        // ls=2 (dist 4): conj w128^{16t}
        #pragma unroll
        for (int q = 0; q < 16; q += 8)
            #pragma unroll
            for (int t = 0; t < 4; ++t) {
                float2 u = x[q+t];
                float2 v = cmulc(x[q+t+4], W2L(16*t));
                x[q+t]   = cadd(u, v);
                x[q+t+4] = csub(u, v);
            }
        // ls=3 (dist 8): conj w128^{8t}
        #pragma unroll
        for (int t = 0; t < 8; ++t) {
            float2 u = x[t];
            float2 v = cmulc(x[t+8], W2L(8*t));
            x[t]   = cadd(u, v);
            x[t+8] = csub(u, v);
        }
        #pragma unroll
        for (int t = 0; t < 16; ++t) buf[base + LDST * t] = x[t];
    }
    __syncthreads();

    // ======== I4: inverse radix-8, stages ls=4,5,6 + output write (rows j+16t) ====
    const float scale = 1.0f / (2.0f * (float)NFFT);
    float* orow = out + (size_t)b * NFFT;
    #pragma unroll
    for (int it = 0; it < 2; ++it) {
        const int idx = tid + (it << 10);
        const int j = idx >> 7;
        const int c = idx & 127;
        const int base = j * LDST + c;
        float2 x[8];
        #pragma unroll
        for (int t = 0; t < 8; ++t) x[t] = buf[base + 16 * LDST * t];
        // ls=4 (dist 1): conj w128^{4j}
        {
            float2 w = W2L(4*j);
            #pragma unroll
            for (int q = 0; q < 8; q += 2) {
                float2 u = x[q];
                float2 v = cmulc(x[q+1], w);
                x[q]   = cadd(u, v);
                x[q+1] = csub(u, v);
            }
        }
        // ls=5 (dist 2): conj w128^{2(j+16t)}, t=0,1
        #pragma unroll
        for (int q = 0; q < 8; q += 4)
            #pragma unroll
            for (int t = 0; t < 2; ++t) {
                float2 u = x[q+t];
                float2 v = cmulc(x[q+t+2], W2L(2*(j + 16*t)));
                x[q+t]   = cadd(u, v);
                x[q+t+2] = csub(u, v);
            }
        // ls=6 (dist 4): conj w128^{j+16t} — emit Im*scale (guarded: c < 125)
        float ylo[4], yhi[4];
        #pragma unroll
        for (int t = 0; t < 4; ++t) {
            float2 u = x[t];
            float2 v = cmulc(x[t+4], W2L(j + 16*t));
            ylo[t] = (u.y + v.y) * scale;
            yhi[t] = (u.y - v.y) * scale;
        }
        if (c < NCCOL) {
            const int gbase = j * NCCOL + c;
            #pragma unroll
            for (int t = 0; t < 4; ++t) {
                orow[gbase + 2000 * t]       = ylo[t];
                orow[gbase + 2000 * (t + 4)] = yhi[t];
            }
        }
    }
}

extern "C" void kernel_launch(void* const* d_in, const int* in_sizes, int n_in,
                              void* d_out, int out_size, void* d_ws, size_t ws_size,
                              hipStream_t stream)
{
    const float* img  = (const float*)d_in[0];
    const float* seq  = (const float*)d_in[1];
    const int*   hvec = (const int*)d_in[2];
    const float* svec = (const float*)d_in[3];
    float* out = (float*)d_out;

    const int B = in_sizes[0] / DFEAT;   // 2048
    const size_t lds_bytes = (size_t)LDSN * sizeof(float2);  // 136680 B

    const bool use_lut = ws_size >= (size_t)DATN * sizeof(float2);  // 135168 B
    float2* cross = use_lut ? (float2*)d_ws : nullptr;
    if (use_lut) {
        hipLaunchKernelGGL(fill_cross_lut_pad, dim3((DATN + 255) / 256), dim3(256), 0,
                           stream, cross);
    }

    hipFuncSetAttribute((const void*)mcb_fft_conv_kernel,
                        hipFuncAttributeMaxDynamicSharedMemorySize,
                        (int)lds_bytes);

    hipLaunchKernelGGL(mcb_fft_conv_kernel, dim3(B), dim3(TPB), lds_bytes, stream,
                       img, seq, hvec, svec, out, cross);
}